// Round 6
// baseline (303.511 us; speedup 1.0000x reference)
//
#include <hip/hip_runtime.h>

#define D_MODEL 2048
#define ADAPTER 64
#define RPB     16          // rows per block
#define THREADS 256
#define NROWS   16384       // 4 * 4096

typedef __attribute__((ext_vector_type(4))) float f32x4;
typedef __attribute__((ext_vector_type(8))) short bf16x8;
typedef __attribute__((ext_vector_type(4))) unsigned short u16x4;
typedef __attribute__((ext_vector_type(8))) unsigned short u16x8;

__device__ __forceinline__ unsigned short f2bf(float f) {
    unsigned int u = __float_as_uint(f);
    u += 0x7fffu + ((u >> 16) & 1u);       // round-to-nearest-even
    return (unsigned short)(u >> 16);
}
__device__ __forceinline__ float bf2f(unsigned short u) {
    return __uint_as_float(((unsigned int)u) << 16);
}

// ---- prep: fp32 weights -> bf16 in workspace ------------------------------
__global__ __launch_bounds__(256)
void weights_to_bf16(const float* __restrict__ dw, const float* __restrict__ uw,
                     unsigned short* __restrict__ dwb, unsigned short* __restrict__ uwb)
{
    const int i = 4 * (blockIdx.x * 256 + threadIdx.x);   // 128 blocks
    f32x4 a = *(const f32x4*)(dw + i);
    f32x4 b = *(const f32x4*)(uw + i);
    u16x4 ra, rb;
#pragma unroll
    for (int j = 0; j < 4; ++j) { ra[j] = f2bf(a[j]); rb[j] = f2bf(b[j]); }
    *(u16x4*)(dwb + i) = ra;
    *(u16x4*)(uwb + i) = rb;
}

// ---- main fused kernel ----------------------------------------------------
// LDS x swizzle: byte_off ^= (row&7)<<4  (T2; preserves 8B/16B alignment)
__global__ __launch_bounds__(THREADS, 2)
void houlsby_fused(const float* __restrict__ x,
                   const float* __restrict__ lnw,
                   const float* __restrict__ lnb,
                   const unsigned short* __restrict__ dwb,  // bf16 [64][2048]
                   const float* __restrict__ db,            // [64]
                   const unsigned short* __restrict__ uwb,  // bf16 [2048][64]
                   const float* __restrict__ ub,            // [2048]
                   float* __restrict__ out)
{
    __shared__ __align__(16) unsigned short xl[RPB * D_MODEL];   // 64 KB: raw -> LN'ed bf16 (swizzled)
    __shared__ __align__(16) unsigned short Hl[RPB][ADAPTER + 8];

    const int tid = threadIdx.x;
    const int w   = tid >> 6;      // wave 0..3
    const int l   = tid & 63;      // lane
    const int rowBase = blockIdx.x * RPB;

    // ---------- Pass A: stream x once: stats (regs) + raw bf16 -> swizzled LDS ----------
    float rsv[4], nmrv[4];
    for (int rr = 0; rr < 4; ++rr) {
        const int row = 4 * w + rr;
        const float* xr = x + (size_t)(rowBase + row) * D_MODEL;
        char* xrow_l = (char*)(xl + row * D_MODEL);
        const int swz = (row & 7) << 4;
        float s = 0.f, sq = 0.f;
#pragma unroll
        for (int j = 0; j < 8; ++j) {
            f32x4 v = *(const f32x4*)(xr + 4 * l + 256 * j);
            s  += v.x + v.y + v.z + v.w;
            sq += v.x * v.x + v.y * v.y + v.z * v.z + v.w * v.w;
            u16x4 hv;
#pragma unroll
            for (int k = 0; k < 4; ++k) hv[k] = f2bf(v[k]);
            *(u16x4*)(xrow_l + (((4 * l + 256 * j) * 2) ^ swz)) = hv;
        }
#pragma unroll
        for (int off = 32; off; off >>= 1) {
            s  += __shfl_xor(s,  off, 64);
            sq += __shfl_xor(sq, off, 64);
        }
        const float mu  = s * (1.f / D_MODEL);
        const float var = sq * (1.f / D_MODEL) - mu * mu;
        const float rs  = rsqrtf(var + 1e-5f);
        rsv[rr]  = rs;
        nmrv[rr] = -mu * rs;
    }

    // ---------- Pass A2: in-place LN normalize of own rows (no barrier needed) ----------
    for (int rr = 0; rr < 4; ++rr) {
        const int row = 4 * w + rr;
        char* xrow_l = (char*)(xl + row * D_MODEL);
        const int swz = (row & 7) << 4;
        const float rs = rsv[rr], nmr = nmrv[rr];
#pragma unroll
        for (int j = 0; j < 4; ++j) {
            const int e0 = 8 * l + 512 * j;                 // element index, 16B aligned
            char* p = xrow_l + ((2 * e0) ^ swz);
            u16x8 xv = *(const u16x8*)p;
            f32x4 lw0 = *(const f32x4*)(lnw + e0);
            f32x4 lw1 = *(const f32x4*)(lnw + e0 + 4);
            f32x4 lb0 = *(const f32x4*)(lnb + e0);
            f32x4 lb1 = *(const f32x4*)(lnb + e0 + 4);
            u16x8 hv;
#pragma unroll
            for (int k = 0; k < 4; ++k) {
                hv[k]     = f2bf(fmaf(fmaf(bf2f(xv[k]),     rs, nmr), lw0[k], lb0[k]));
                hv[4 + k] = f2bf(fmaf(fmaf(bf2f(xv[4 + k]), rs, nmr), lw1[k], lb1[k]));
            }
            *(u16x8*)p = hv;
        }
    }
    __syncthreads();

    // ---------- Phase 2: down-proj GEMM (M=16, N=64, K=2048) ----------
    const int m  = l & 15;
    const int g  = l >> 4;

    const int a0 = 16 * w + m;
    const unsigned short* dwr = dwb + a0 * D_MODEL;
    const char* xrow_l = (const char*)(xl + m * D_MODEL);
    const int swzm = (m & 7) << 4;

    f32x4 acc = {0.f, 0.f, 0.f, 0.f};

#pragma unroll 8
    for (int ks = 0; ks < 64; ++ks) {
        const int kb = 32 * ks + 8 * g;                        // k element index
        const bf16x8 af = *(const bf16x8*)(xrow_l + ((2 * kb) ^ swzm));  // LN'ed x
        const bf16x8 bw = *(const bf16x8*)(dwr + kb);           // L2-hot stream
        acc = __builtin_amdgcn_mfma_f32_16x16x32_bf16(af, bw, acc, 0, 0, 0);
    }

    // ---------- Phase 3: bias + relu -> H (bf16) in LDS ----------
    {
        const float dbv = db[a0];
#pragma unroll
        for (int r = 0; r < 4; ++r) {
            const float h = fmaxf(acc[r] + dbv, 0.f);
            Hl[4 * g + r][a0] = f2bf(h);       // D layout: row = 4*(lane>>4)+reg
        }
    }
    __syncthreads();

    // ---------- Phase 4: up-proj, operand-swapped (A=uw, B=H) + residual ----------
    bf16x8 Hf[2];
#pragma unroll
    for (int ks = 0; ks < 2; ++ks)
        Hf[ks] = *(const bf16x8*)(&Hl[m][32 * ks + 8 * g]);

    const int dBase = 512 * w;
    const size_t orow = (size_t)(rowBase + m) * D_MODEL;
#pragma unroll 4
    for (int nt = 0; nt < 32; ++nt) {
        const int d0 = dBase + 16 * nt;
        const unsigned short* uwr = uwb + (d0 + m) * ADAPTER;
        const bf16x8 A0 = *(const bf16x8*)(uwr + 8 * g);
        const bf16x8 A1 = *(const bf16x8*)(uwr + 32 + 8 * g);

        f32x4 c = {0.f, 0.f, 0.f, 0.f};
        c = __builtin_amdgcn_mfma_f32_16x16x32_bf16(A0, Hf[0], c, 0, 0, 0);
        c = __builtin_amdgcn_mfma_f32_16x16x32_bf16(A1, Hf[1], c, 0, 0, 0);

        const int dcol = d0 + 4 * g;
        const f32x4 ubv  = *(const f32x4*)(ub + dcol);
        const f32x4 xres = *(const f32x4*)(x + orow + dcol);   // exact fp32 residual (L2/L3-hot)
        f32x4 o;
#pragma unroll
        for (int r = 0; r < 4; ++r)
            o[r] = xres[r] + c[r] + ubv[r];
        *(f32x4*)(out + orow + dcol) = o;
    }
}

extern "C" void kernel_launch(void* const* d_in, const int* in_sizes, int n_in,
                              void* d_out, int out_size, void* d_ws, size_t ws_size,
                              hipStream_t stream) {
    const float* x   = (const float*)d_in[0];
    const float* lnw = (const float*)d_in[1];
    const float* lnb = (const float*)d_in[2];
    const float* dw  = (const float*)d_in[3];
    const float* db  = (const float*)d_in[4];
    const float* uw  = (const float*)d_in[5];
    const float* ub  = (const float*)d_in[6];
    float* out = (float*)d_out;

    unsigned short* dwb = (unsigned short*)d_ws;                       // 256 KiB
    unsigned short* uwb = (unsigned short*)((char*)d_ws + 64 * 2048 * 2);

    weights_to_bf16<<<dim3(128), dim3(256), 0, stream>>>(dw, uw, dwb, uwb);

    dim3 grid(NROWS / RPB);   // 1024 blocks
    dim3 block(THREADS);
    houlsby_fused<<<grid, block, 0, stream>>>(x, lnw, lnb, dwb, db, uwb, ub, out);
}